// Round 21
// baseline (338.121 us; speedup 1.0000x reference)
//
#include <hip/hip_runtime.h>

namespace {

constexpr int TT = 512;   // timesteps
constexpr int H  = 64;    // hidden units per layer
constexpr int NB = 8;     // real batches per block; MFMA cols 8..15 duplicate h
constexpr int NT = 512;   // 8 waves: 0-3 -> layer0, 4-7 -> layer1
constexpr float L2E = 1.442695041f;

typedef float  f32x4  __attribute__((ext_vector_type(4)));
typedef short  bf16x8 __attribute__((ext_vector_type(8)));

#define MFMA(A, B, C) (C) = __builtin_amdgcn_mfma_f32_16x16x32_bf16((A), (B), (C), 0, 0, 0)

__device__ __forceinline__ float exp2_hw(float x) {
    float r; asm("v_exp_f32 %0, %1" : "=v"(r) : "v"(x)); return r;
}
// Fused activations: 8 trans per (unit,batch) pair (vs 10 unfused).
//   zi,zf,zo pre-scaled by -log2e; zg by -2log2e.
//   c' = sigm(f)*c + sigm(i)*tanh(g);  h = sigm(o)*tanh(c')
__device__ __forceinline__ float act_pair(float zi, float zf, float zg, float zo,
                                          float& c) {
    const float ei = exp2_hw(zi);
    const float ef = exp2_hw(zf);
    const float eg = exp2_hw(zg);
    const float eo = exp2_hw(zo);
    const float sf = __builtin_amdgcn_rcpf(1.0f + ef);
    const float P  = (1.0f - eg) * __builtin_amdgcn_rcpf((1.0f + ei) * (1.0f + eg));
    c = fmaf(sf, c, P);
    const float ec = exp2_hw(-2.885390082f * c);
    return (1.0f - ec) * __builtin_amdgcn_rcpf((1.0f + eo) * (1.0f + ec));
}
__device__ __forceinline__ unsigned short f2bf(float f) {
    unsigned u = __float_as_uint(f);
    return (unsigned short)((u + 0x7fffu + ((u >> 16) & 1u)) >> 16);
}
__device__ __forceinline__ float bf2f(unsigned short s) {
    return __uint_as_float(((unsigned)s) << 16);
}

__device__ __forceinline__ void waitge(int* c, int v) {
    while (__hip_atomic_load(c, __ATOMIC_ACQUIRE, __HIP_MEMORY_SCOPE_WORKGROUP) < v) {}
}
__device__ __forceinline__ void signal(int* c) {
    if ((threadIdx.x & 63) == 0)
        (void)__hip_atomic_fetch_add(c, 1, __ATOMIC_RELEASE, __HIP_MEMORY_SCOPE_WORKGROUP);
}

// ---- ws layout (unchanged; main kernel reads only the hi half) ----
//  L0: ushort off = (wloc*64+lane)*128 + i*16          i<8  (i=j*2+kt), hi +0, lo +8
//  L1: ushort off = 32768 + (wloc*64+lane)*256 + i*16  i<16 (i=j*4+kt)
// Rows pre-scaled by -log2e (-2log2e for g-gate rows).

__global__ void prep_weights(const float* __restrict__ W_hh0,
                             const float* __restrict__ W_ih1,
                             const float* __restrict__ W_hh1,
                             unsigned short* __restrict__ ws)
{
    const int id = blockIdx.x * blockDim.x + threadIdx.x;   // 0..6143
    int wl, lane, i, j, kt;
    const float* src;
    size_t dst;
    if (id < 2048) {                 // L0
        wl = id >> 9; lane = (id >> 3) & 63; i = id & 7;
        j = i >> 1; kt = i & 1;
        const int lr = lane & 15, lg = lane >> 4;
        const int row = j * 64 + 16 * wl + lr;
        src = W_hh0 + row * 64 + kt * 32 + lg * 8;
        dst = (size_t)((wl * 64 + lane) * 8 + i) * 16;
    } else {                         // L1
        const int id2 = id - 2048;
        wl = id2 >> 10; lane = (id2 >> 4) & 63; i = id2 & 15;
        j = i >> 2; kt = i & 3;
        const int lr = lane & 15, lg = lane >> 4;
        const int row = j * 64 + 16 * wl + lr;
        src = (kt < 2) ? (W_ih1 + row * 64 + kt * 32 + lg * 8)
                       : (W_hh1 + row * 64 + (kt - 2) * 32 + lg * 8);
        dst = 32768 + (size_t)((wl * 64 + lane) * 16 + i) * 16;
    }
    const float sj = (j == 2) ? (-2.0f * L2E) : (-L2E);
    float4 a = *(const float4*)src;
    float4 b = *(const float4*)(src + 4);
    float t[8] = {a.x * sj, a.y * sj, a.z * sj, a.w * sj,
                  b.x * sj, b.y * sj, b.z * sj, b.w * sj};
    bf16x8 hi, lo;
    #pragma unroll
    for (int e = 0; e < 8; ++e) {
        unsigned short h = f2bf(t[e]);
        hi[e] = (short)h;
        lo[e] = (short)f2bf(t[e] - bf2f(h));
    }
    *(bf16x8*)(ws + dst)     = hi;
    *(bf16x8*)(ws + dst + 8) = lo;
}

__global__ __launch_bounds__(NT)
__attribute__((amdgpu_waves_per_eu(2, 2)))
void lstm2_mfma_kernel(
    const float* __restrict__ x,
    const unsigned short* __restrict__ wfrag,
    const float* __restrict__ W_ih0,
    const float* __restrict__ b_ih0, const float* __restrict__ b_hh0,
    const float* __restrict__ b_ih1, const float* __restrict__ b_hh1,
    const float* __restrict__ fc_W,  const float* __restrict__ fc_b,
    float* __restrict__ out)
{
    // frag buffers: cols 0-7 = h(b0..7); cols 8-15 = WRITTEN duplicates
    // (write-both scheme, R17-proven). Reads use fro = lane*8 -> 64 distinct
    // contiguous 16B addresses, conflict-free (fixes R18's 1.36e7 conflicts
    // from same-address dup-on-read).
    __shared__ alignas(16) unsigned short h1ring[4][1024];   // 8 KB
    __shared__ alignas(16) unsigned short h2buf[2][1024];    // 4 KB
    __shared__ float x_lds2[TT][NB];                         // 16 KB, [t][b]
    __shared__ float fc_part[32][NB];
    __shared__ int c0, c1c, c1d;

    const int tid  = threadIdx.x;
    const int lane = tid & 63;
    const int wid  = tid >> 6;          // 0..7
    const int wloc = wid & 3;
    const bool isL1 = wid >= 4;
    const int lr = lane & 15;           // col: batch (0-7); 8-15 dup
    const int lg = lane >> 4;
    const int b0 = blockIdx.x * NB;
    const bool lo8 = (lr < 8);
    const int rb = lo8 ? 0 : 2;         // r-split: which 2 acc slots this lane activates

    // ---- stage x transposed ----
    {
        const float4* xs = (const float4*)(x + (size_t)b0 * TT);
        #pragma unroll
        for (int i = 0; i < 2; ++i) {
            int idx = i * NT + tid;
            float4 v = xs[idx];
            int b  = idx >> 7;
            int t4 = (idx & 127) << 2;
            x_lds2[t4 + 0][b] = v.x;
            x_lds2[t4 + 1][b] = v.y;
            x_lds2[t4 + 2][b] = v.z;
            x_lds2[t4 + 3][b] = v.w;
        }
    }
    // ---- zero h buffers ----
    {
        int* hz = (int*)h1ring;
        #pragma unroll
        for (int i = 0; i < 4; ++i) hz[i * NT + tid] = 0;
        int* h2z = (int*)h2buf;
        #pragma unroll
        for (int i = 0; i < 2; ++i) h2z[i * NT + tid] = 0;
    }
    if (tid == 0) { c0 = 0; c1c = 0; c1d = 0; }

    // ---- per-wave static weights: W_hi fragments only ----
    bf16x8 Ahi[16];
    float bias[16], wxv[16];
    f32x4 bias4[4];                     // L1: bias as MFMA C-operand
    float cst0 = 0.f, cst1 = 0.f;
    const int base_u = 16 * wloc + 4 * lg;
    const int u0 = base_u + rb;
    const int wo  = ((lr & 7) + 16 * (base_u >> 3)) * 8 + (base_u & 7) + rb;
    const int fro = lane * 8;           // distinct per-lane reads (conflict-free)

    if (!isL1) {
        const unsigned short* wb = wfrag + ((wloc * 64 + lane) << 7);
        #pragma unroll
        for (int i = 0; i < 8; ++i)
            Ahi[i] = *(const bf16x8*)(wb + i * 16);
        #pragma unroll
        for (int j = 0; j < 4; ++j) {
            const float sj = (j == 2) ? (-2.0f * L2E) : (-L2E);
            const int rowc = j * 64 + base_u;
            #pragma unroll
            for (int r = 0; r < 4; ++r) {
                bias[j * 4 + r] = (b_ih0[rowc + r] + b_hh0[rowc + r]) * sj;
                wxv [j * 4 + r] = W_ih0[rowc + r] * sj;
            }
        }
    } else {
        const unsigned short* wb = wfrag + 32768 + ((wloc * 64 + lane) << 8);
        #pragma unroll
        for (int i = 0; i < 16; ++i)
            Ahi[i] = *(const bf16x8*)(wb + i * 16);
        #pragma unroll
        for (int j = 0; j < 4; ++j) {
            const float sj = (j == 2) ? (-2.0f * L2E) : (-L2E);
            const int rowc = j * 64 + base_u;
            #pragma unroll
            for (int r = 0; r < 4; ++r)
                bias4[j][r] = (b_ih1[rowc + r] + b_hh1[rowc + r]) * sj;
        }
    }

    __syncthreads();

    if (!isL1) {
        // ============ L0: computes h1(t). Chain: peers' h1(t-1) -> h1(t) ============
        for (int t = 0; t < TT; ++t) {
            const float xv = x_lds2[t][lane & 7];
            f32x4 acc[4];
            #pragma unroll
            for (int j = 0; j < 4; ++j)
                #pragma unroll
                for (int r = 0; r < 4; ++r)
                    acc[j][r] = fmaf(wxv[j * 4 + r], xv, bias[j * 4 + r]);
            if (t >= 4) waitge(&c1c, 4 * (t - 3));     // ring slot t&3 consumed by L1
            waitge(&c0, 4 * t);                        // peers wrote h1(t-1)
            const unsigned short* ph = &h1ring[(t - 1) & 3][0];
            bf16x8 Bh0 = *(const bf16x8*)(ph + fro);
            bf16x8 Bh1 = *(const bf16x8*)(ph + 512 + fro);
            #pragma unroll
            for (int j = 0; j < 4; ++j) MFMA(Ahi[j * 2 + 0], Bh0, acc[j]);
            #pragma unroll
            for (int j = 0; j < 4; ++j) MFMA(Ahi[j * 2 + 1], Bh1, acc[j]);
            // r-split select — dup cols carry identical acc values
            const float zi0 = lo8 ? acc[0][0] : acc[0][2];
            const float zi1 = lo8 ? acc[0][1] : acc[0][3];
            const float zf0 = lo8 ? acc[1][0] : acc[1][2];
            const float zf1 = lo8 ? acc[1][1] : acc[1][3];
            const float zg0 = lo8 ? acc[2][0] : acc[2][2];
            const float zg1 = lo8 ? acc[2][1] : acc[2][3];
            const float zo0 = lo8 ? acc[3][0] : acc[3][2];
            const float zo1 = lo8 ? acc[3][1] : acc[3][3];
            const float hv0 = act_pair(zi0, zf0, zg0, zo0, cst0);
            const float hv1 = act_pair(zi1, zf1, zg1, zo1, cst1);
            unsigned p;
            asm("v_cvt_pk_bf16_f32 %0, %1, %2" : "=v"(p) : "v"(hv0), "v"(hv1));
            *(unsigned*)&h1ring[t & 3][wo]      = p;    // col c
            *(unsigned*)&h1ring[t & 3][wo + 64] = p;    // col c+8 duplicate
            signal(&c0);
        }
    } else {
        // ============ L1 (software-pipelined): iter t computes h2(t-1) ============
        f32x4 acc[4];
        bf16x8 B0, B1;
        // prologue: prefetch h1(0), kt01 with bias as MFMA C-operand
        waitge(&c0, 4);
        {
            const unsigned short* p1 = &h1ring[0][0];
            B0 = *(const bf16x8*)(p1 + fro);
            B1 = *(const bf16x8*)(p1 + 512 + fro);
        }
        signal(&c1c);                         // consumed h1(0)
        #pragma unroll
        for (int j = 0; j < 4; ++j)
            acc[j] = __builtin_amdgcn_mfma_f32_16x16x32_bf16(Ahi[j * 4 + 0], B0,
                                                             bias4[j], 0, 0, 0);
        #pragma unroll
        for (int j = 0; j < 4; ++j) MFMA(Ahi[j * 4 + 1], B1, acc[j]);

        for (int t = 1; t <= TT; ++t) {
            // ---- critical section: h2(t-2) -> h2(t-1) ----
            waitge(&c1d, 4 * (t - 1));                // peers wrote h2(t-2)
            const unsigned short* p2 = &h2buf[(t - 2) & 1][0];
            bf16x8 B2 = *(const bf16x8*)(p2 + fro);
            bf16x8 B3 = *(const bf16x8*)(p2 + 512 + fro);
            #pragma unroll
            for (int j = 0; j < 4; ++j) MFMA(Ahi[j * 4 + 2], B2, acc[j]);
            #pragma unroll
            for (int j = 0; j < 4; ++j) MFMA(Ahi[j * 4 + 3], B3, acc[j]);
            const float zi0 = lo8 ? acc[0][0] : acc[0][2];
            const float zi1 = lo8 ? acc[0][1] : acc[0][3];
            const float zf0 = lo8 ? acc[1][0] : acc[1][2];
            const float zf1 = lo8 ? acc[1][1] : acc[1][3];
            const float zg0 = lo8 ? acc[2][0] : acc[2][2];
            const float zg1 = lo8 ? acc[2][1] : acc[2][3];
            const float zo0 = lo8 ? acc[3][0] : acc[3][2];
            const float zo1 = lo8 ? acc[3][1] : acc[3][3];
            const float hv0 = act_pair(zi0, zf0, zg0, zo0, cst0);
            const float hv1 = act_pair(zi1, zf1, zg1, zo1, cst1);
            unsigned p;
            asm("v_cvt_pk_bf16_f32 %0, %1, %2" : "=v"(p) : "v"(hv0), "v"(hv1));
            *(unsigned*)&h2buf[(t - 1) & 1][wo]      = p;
            *(unsigned*)&h2buf[(t - 1) & 1][wo + 64] = p;
            signal(&c1d);
            // ---- off-critical: prefetch h1(t) and run kt01 for iter t+1 ----
            if (t < TT) {
                waitge(&c0, 4 * (t + 1));             // L0 ~4 ahead: fast path
                const unsigned short* p1 = &h1ring[t & 3][0];
                B0 = *(const bf16x8*)(p1 + fro);
                B1 = *(const bf16x8*)(p1 + 512 + fro);
                signal(&c1c);                         // consumed h1(t)
                #pragma unroll
                for (int j = 0; j < 4; ++j)
                    acc[j] = __builtin_amdgcn_mfma_f32_16x16x32_bf16(Ahi[j * 4 + 0],
                                                                     B0, bias4[j],
                                                                     0, 0, 0);
                #pragma unroll
                for (int j = 0; j < 4; ++j) MFMA(Ahi[j * 4 + 1], B1, acc[j]);
            } else {
                const float s = fc_W[u0] * hv0 + fc_W[u0 + 1] * hv1;
                fc_part[(wid - 4) * 8 + lg * 2 + (lo8 ? 0 : 1)][lr & 7] = s;
            }
        }
    }

    __syncthreads();

    // ---- final FC reduce (deterministic) ----
    if (tid < NB) {
        float s = fc_b[0];
        #pragma unroll
        for (int i = 0; i < 32; ++i) s += fc_part[i][tid];
        out[b0 + tid] = s;
    }
}

} // namespace

extern "C" void kernel_launch(void* const* d_in, const int* in_sizes, int n_in,
                              void* d_out, int out_size, void* d_ws, size_t ws_size,
                              hipStream_t stream)
{
    const float* x     = (const float*)d_in[0];
    const float* W_ih0 = (const float*)d_in[1];
    const float* W_hh0 = (const float*)d_in[2];
    const float* b_ih0 = (const float*)d_in[3];
    const float* b_hh0 = (const float*)d_in[4];
    const float* W_ih1 = (const float*)d_in[5];
    const float* W_hh1 = (const float*)d_in[6];
    const float* b_ih1 = (const float*)d_in[7];
    const float* b_hh1 = (const float*)d_in[8];
    const float* fc_W  = (const float*)d_in[9];
    const float* fc_b  = (const float*)d_in[10];
    float* out = (float*)d_out;
    unsigned short* ws = (unsigned short*)d_ws;    // 192 KB of pre-split fragments

    // 1) pre-split weight fragments into d_ws (contiguous per-lane runs)
    hipLaunchKernelGGL(prep_weights, dim3(24), dim3(256), 0, stream,
                       W_hh0, W_ih1, W_hh1, ws);

    // 2) main recurrent kernel
    const int B = in_sizes[0] / TT;          // 2048
    dim3 grid(B / NB), block(NT);            // 256 blocks x 512 threads
    hipLaunchKernelGGL(lstm2_mfma_kernel, grid, block, 0, stream,
                       x, ws, W_ih0, b_ih0, b_hh0, b_ih1, b_hh1, fc_W, fc_b, out);
}

// Round 22
// 329.730 us; speedup vs baseline: 1.0254x; 1.0254x over previous
//
#include <hip/hip_runtime.h>

namespace {

constexpr int TT = 512;   // timesteps
constexpr int H  = 64;    // hidden units per layer
constexpr int NB = 8;     // real batches per block; MFMA cols 8..15 dup via READ addr
constexpr int NT = 512;   // 8 waves: 0-3 -> layer0, 4-7 -> layer1
constexpr float L2E = 1.442695041f;

typedef float  f32x4  __attribute__((ext_vector_type(4)));
typedef short  bf16x8 __attribute__((ext_vector_type(8)));

#define MFMA(A, B, C) (C) = __builtin_amdgcn_mfma_f32_16x16x32_bf16((A), (B), (C), 0, 0, 0)

__device__ __forceinline__ float exp2_hw(float x) {
    float r; asm("v_exp_f32 %0, %1" : "=v"(r) : "v"(x)); return r;
}
// Fused activations: 8 trans per (unit,batch) pair (vs 10 unfused).
//   zi,zf,zo pre-scaled by -log2e; zg by -2log2e.
//   c' = sigm(f)*c + sigm(i)*tanh(g);  h = sigm(o)*tanh(c')
__device__ __forceinline__ float act_pair(float zi, float zf, float zg, float zo,
                                          float& c) {
    const float ei = exp2_hw(zi);
    const float ef = exp2_hw(zf);
    const float eg = exp2_hw(zg);
    const float eo = exp2_hw(zo);
    const float sf = __builtin_amdgcn_rcpf(1.0f + ef);
    const float P  = (1.0f - eg) * __builtin_amdgcn_rcpf((1.0f + ei) * (1.0f + eg));
    c = fmaf(sf, c, P);
    const float ec = exp2_hw(-2.885390082f * c);
    return (1.0f - ec) * __builtin_amdgcn_rcpf((1.0f + eo) * (1.0f + ec));
}
__device__ __forceinline__ unsigned short f2bf(float f) {
    unsigned u = __float_as_uint(f);
    return (unsigned short)((u + 0x7fffu + ((u >> 16) & 1u)) >> 16);
}
__device__ __forceinline__ float bf2f(unsigned short s) {
    return __uint_as_float(((unsigned)s) << 16);
}

__device__ __forceinline__ void waitge(int* c, int v) {
    while (__hip_atomic_load(c, __ATOMIC_ACQUIRE, __HIP_MEMORY_SCOPE_WORKGROUP) < v) {}
}
__device__ __forceinline__ void signal(int* c) {
    if ((threadIdx.x & 63) == 0)
        (void)__hip_atomic_fetch_add(c, 1, __ATOMIC_RELEASE, __HIP_MEMORY_SCOPE_WORKGROUP);
}

// ---- ws layout (main kernel reads only the hi half) ----
//  L0: ushort off = (wloc*64+lane)*128 + i*16          i<8  (i=j*2+kt), hi +0, lo +8
//  L1: ushort off = 32768 + (wloc*64+lane)*256 + i*16  i<16 (i=j*4+kt)
// Rows pre-scaled by -log2e (-2log2e for g-gate rows).

__global__ void prep_weights(const float* __restrict__ W_hh0,
                             const float* __restrict__ W_ih1,
                             const float* __restrict__ W_hh1,
                             unsigned short* __restrict__ ws)
{
    const int id = blockIdx.x * blockDim.x + threadIdx.x;   // 0..6143
    int wl, lane, i, j, kt;
    const float* src;
    size_t dst;
    if (id < 2048) {                 // L0
        wl = id >> 9; lane = (id >> 3) & 63; i = id & 7;
        j = i >> 1; kt = i & 1;
        const int lr = lane & 15, lg = lane >> 4;
        const int row = j * 64 + 16 * wl + lr;
        src = W_hh0 + row * 64 + kt * 32 + lg * 8;
        dst = (size_t)((wl * 64 + lane) * 8 + i) * 16;
    } else {                         // L1
        const int id2 = id - 2048;
        wl = id2 >> 10; lane = (id2 >> 4) & 63; i = id2 & 15;
        j = i >> 2; kt = i & 3;
        const int lr = lane & 15, lg = lane >> 4;
        const int row = j * 64 + 16 * wl + lr;
        src = (kt < 2) ? (W_ih1 + row * 64 + kt * 32 + lg * 8)
                       : (W_hh1 + row * 64 + (kt - 2) * 32 + lg * 8);
        dst = 32768 + (size_t)((wl * 64 + lane) * 16 + i) * 16;
    }
    const float sj = (j == 2) ? (-2.0f * L2E) : (-L2E);
    float4 a = *(const float4*)src;
    float4 b = *(const float4*)(src + 4);
    float t[8] = {a.x * sj, a.y * sj, a.z * sj, a.w * sj,
                  b.x * sj, b.y * sj, b.z * sj, b.w * sj};
    bf16x8 hi, lo;
    #pragma unroll
    for (int e = 0; e < 8; ++e) {
        unsigned short h = f2bf(t[e]);
        hi[e] = (short)h;
        lo[e] = (short)f2bf(t[e] - bf2f(h));
    }
    *(bf16x8*)(ws + dst)     = hi;
    *(bf16x8*)(ws + dst + 8) = lo;
}

__global__ __launch_bounds__(NT)
__attribute__((amdgpu_waves_per_eu(2, 2)))
void lstm2_mfma_kernel(
    const float* __restrict__ x,
    const unsigned short* __restrict__ wfrag,
    const float* __restrict__ W_ih0,
    const float* __restrict__ b_ih0, const float* __restrict__ b_hh0,
    const float* __restrict__ b_ih1, const float* __restrict__ b_hh1,
    const float* __restrict__ fc_W,  const float* __restrict__ fc_b,
    float* __restrict__ out)
{
    // frag buffers: only cols 0-7 are written; cols 8-15 duplicate via READ
    // addressing (fro = (lane & ~8)*8 -> lanes lr and lr+8 read the same 16B).
    __shared__ alignas(16) unsigned short h1ring[4][1024];   // 8 KB
    __shared__ alignas(16) unsigned short h2buf[2][1024];    // 4 KB
    __shared__ float x_lds2[TT][NB];                         // 16 KB, [t][b]
    __shared__ float fc_part[32][NB];
    __shared__ int c0, c1c, c1d;

    const int tid  = threadIdx.x;
    const int lane = tid & 63;
    const int wid  = tid >> 6;          // 0..7
    const int wloc = wid & 3;
    const bool isL1 = wid >= 4;
    const int lr = lane & 15;           // col: batch (0-7); 8-15 dup via read addr
    const int lg = lane >> 4;
    const int b0 = blockIdx.x * NB;
    const bool lo8 = (lr < 8);
    const int rb = lo8 ? 0 : 2;         // r-split: which 2 acc slots this lane activates

    // ---- stage x transposed ----
    {
        const float4* xs = (const float4*)(x + (size_t)b0 * TT);
        #pragma unroll
        for (int i = 0; i < 2; ++i) {
            int idx = i * NT + tid;
            float4 v = xs[idx];
            int b  = idx >> 7;
            int t4 = (idx & 127) << 2;
            x_lds2[t4 + 0][b] = v.x;
            x_lds2[t4 + 1][b] = v.y;
            x_lds2[t4 + 2][b] = v.z;
            x_lds2[t4 + 3][b] = v.w;
        }
    }
    // ---- zero h buffers ----
    {
        int* hz = (int*)h1ring;
        #pragma unroll
        for (int i = 0; i < 4; ++i) hz[i * NT + tid] = 0;
        int* h2z = (int*)h2buf;
        #pragma unroll
        for (int i = 0; i < 2; ++i) h2z[i * NT + tid] = 0;
    }
    if (tid == 0) { c0 = 0; c1c = 0; c1d = 0; }

    // ---- per-wave static weights: W_hi fragments only ----
    bf16x8 Ahi[16];
    float bias[16], wxv[16];
    f32x4 bias4[4];                     // L1: bias as MFMA C-operand (no init movs)
    float cst0 = 0.f, cst1 = 0.f;
    const int base_u = 16 * wloc + 4 * lg;
    const int u0 = base_u + rb;
    const int wo  = ((lr & 7) + 16 * (base_u >> 3)) * 8 + (base_u & 7) + rb;
    const int fro = (lane & ~8) * 8;    // duplicate-on-read: col = lr & 7

    if (!isL1) {
        const unsigned short* wb = wfrag + ((wloc * 64 + lane) << 7);
        #pragma unroll
        for (int i = 0; i < 8; ++i)
            Ahi[i] = *(const bf16x8*)(wb + i * 16);
        #pragma unroll
        for (int j = 0; j < 4; ++j) {
            const float sj = (j == 2) ? (-2.0f * L2E) : (-L2E);
            const int rowc = j * 64 + base_u;
            #pragma unroll
            for (int r = 0; r < 4; ++r) {
                bias[j * 4 + r] = (b_ih0[rowc + r] + b_hh0[rowc + r]) * sj;
                wxv [j * 4 + r] = W_ih0[rowc + r] * sj;
            }
        }
    } else {
        const unsigned short* wb = wfrag + 32768 + ((wloc * 64 + lane) << 8);
        #pragma unroll
        for (int i = 0; i < 16; ++i)
            Ahi[i] = *(const bf16x8*)(wb + i * 16);
        #pragma unroll
        for (int j = 0; j < 4; ++j) {
            const float sj = (j == 2) ? (-2.0f * L2E) : (-L2E);
            const int rowc = j * 64 + base_u;
            #pragma unroll
            for (int r = 0; r < 4; ++r)
                bias4[j][r] = (b_ih1[rowc + r] + b_hh1[rowc + r]) * sj;
        }
    }

    __syncthreads();

    if (!isL1) {
        // ============ L0: computes h1(t). Chain: peers' h1(t-1) -> h1(t) ============
        for (int t = 0; t < TT; ++t) {
            const float xv = x_lds2[t][lane & 7];
            f32x4 acc[4];
            #pragma unroll
            for (int j = 0; j < 4; ++j)
                #pragma unroll
                for (int r = 0; r < 4; ++r)
                    acc[j][r] = fmaf(wxv[j * 4 + r], xv, bias[j * 4 + r]);
            if (t >= 4) waitge(&c1c, 4 * (t - 3));     // ring slot t&3 consumed by L1
            waitge(&c0, 4 * t);                        // peers wrote h1(t-1)
            const unsigned short* ph = &h1ring[(t - 1) & 3][0];
            bf16x8 Bh0 = *(const bf16x8*)(ph + fro);
            bf16x8 Bh1 = *(const bf16x8*)(ph + 512 + fro);
            #pragma unroll
            for (int j = 0; j < 4; ++j) MFMA(Ahi[j * 2 + 0], Bh0, acc[j]);
            #pragma unroll
            for (int j = 0; j < 4; ++j) MFMA(Ahi[j * 2 + 1], Bh1, acc[j]);
            // r-split select only — dup cols mean no fold needed
            const float zi0 = lo8 ? acc[0][0] : acc[0][2];
            const float zi1 = lo8 ? acc[0][1] : acc[0][3];
            const float zf0 = lo8 ? acc[1][0] : acc[1][2];
            const float zf1 = lo8 ? acc[1][1] : acc[1][3];
            const float zg0 = lo8 ? acc[2][0] : acc[2][2];
            const float zg1 = lo8 ? acc[2][1] : acc[2][3];
            const float zo0 = lo8 ? acc[3][0] : acc[3][2];
            const float zo1 = lo8 ? acc[3][1] : acc[3][3];
            const float hv0 = act_pair(zi0, zf0, zg0, zo0, cst0);
            const float hv1 = act_pair(zi1, zf1, zg1, zo1, cst1);
            unsigned p;
            asm("v_cvt_pk_bf16_f32 %0, %1, %2" : "=v"(p) : "v"(hv0), "v"(hv1));
            *(unsigned*)&h1ring[t & 3][wo] = p;        // single write; dup on read
            signal(&c0);
        }
    } else {
        // ============ L1 (software-pipelined): iter t computes h2(t-1) ============
        f32x4 acc[4];
        bf16x8 B0, B1;
        // prologue: prefetch h1(0), kt01 with bias as MFMA C-operand
        waitge(&c0, 4);
        {
            const unsigned short* p1 = &h1ring[0][0];
            B0 = *(const bf16x8*)(p1 + fro);
            B1 = *(const bf16x8*)(p1 + 512 + fro);
        }
        signal(&c1c);                         // consumed h1(0)
        #pragma unroll
        for (int j = 0; j < 4; ++j)
            acc[j] = __builtin_amdgcn_mfma_f32_16x16x32_bf16(Ahi[j * 4 + 0], B0,
                                                             bias4[j], 0, 0, 0);
        #pragma unroll
        for (int j = 0; j < 4; ++j) MFMA(Ahi[j * 4 + 1], B1, acc[j]);

        for (int t = 1; t <= TT; ++t) {
            // ---- critical section: h2(t-2) -> h2(t-1) ----
            waitge(&c1d, 4 * (t - 1));                // peers wrote h2(t-2)
            const unsigned short* p2 = &h2buf[(t - 2) & 1][0];
            bf16x8 B2 = *(const bf16x8*)(p2 + fro);
            bf16x8 B3 = *(const bf16x8*)(p2 + 512 + fro);
            #pragma unroll
            for (int j = 0; j < 4; ++j) MFMA(Ahi[j * 4 + 2], B2, acc[j]);
            #pragma unroll
            for (int j = 0; j < 4; ++j) MFMA(Ahi[j * 4 + 3], B3, acc[j]);
            const float zi0 = lo8 ? acc[0][0] : acc[0][2];
            const float zi1 = lo8 ? acc[0][1] : acc[0][3];
            const float zf0 = lo8 ? acc[1][0] : acc[1][2];
            const float zf1 = lo8 ? acc[1][1] : acc[1][3];
            const float zg0 = lo8 ? acc[2][0] : acc[2][2];
            const float zg1 = lo8 ? acc[2][1] : acc[2][3];
            const float zo0 = lo8 ? acc[3][0] : acc[3][2];
            const float zo1 = lo8 ? acc[3][1] : acc[3][3];
            const float hv0 = act_pair(zi0, zf0, zg0, zo0, cst0);
            const float hv1 = act_pair(zi1, zf1, zg1, zo1, cst1);
            unsigned p;
            asm("v_cvt_pk_bf16_f32 %0, %1, %2" : "=v"(p) : "v"(hv0), "v"(hv1));
            *(unsigned*)&h2buf[(t - 1) & 1][wo] = p;  // single write; dup on read
            signal(&c1d);
            // ---- off-critical: prefetch h1(t) and run kt01 for iter t+1 ----
            if (t < TT) {
                waitge(&c0, 4 * (t + 1));             // L0 ~4 ahead: fast path
                const unsigned short* p1 = &h1ring[t & 3][0];
                B0 = *(const bf16x8*)(p1 + fro);
                B1 = *(const bf16x8*)(p1 + 512 + fro);
                signal(&c1c);                         // consumed h1(t)
                #pragma unroll
                for (int j = 0; j < 4; ++j)
                    acc[j] = __builtin_amdgcn_mfma_f32_16x16x32_bf16(Ahi[j * 4 + 0],
                                                                     B0, bias4[j],
                                                                     0, 0, 0);
                #pragma unroll
                for (int j = 0; j < 4; ++j) MFMA(Ahi[j * 4 + 1], B1, acc[j]);
            } else {
                const float s = fc_W[u0] * hv0 + fc_W[u0 + 1] * hv1;
                fc_part[(wid - 4) * 8 + lg * 2 + (lo8 ? 0 : 1)][lr & 7] = s;
            }
        }
    }

    __syncthreads();

    // ---- final FC reduce (deterministic) ----
    if (tid < NB) {
        float s = fc_b[0];
        #pragma unroll
        for (int i = 0; i < 32; ++i) s += fc_part[i][tid];
        out[b0 + tid] = s;
    }
}

} // namespace

extern "C" void kernel_launch(void* const* d_in, const int* in_sizes, int n_in,
                              void* d_out, int out_size, void* d_ws, size_t ws_size,
                              hipStream_t stream)
{
    const float* x     = (const float*)d_in[0];
    const float* W_ih0 = (const float*)d_in[1];
    const float* W_hh0 = (const float*)d_in[2];
    const float* b_ih0 = (const float*)d_in[3];
    const float* b_hh0 = (const float*)d_in[4];
    const float* W_ih1 = (const float*)d_in[5];
    const float* W_hh1 = (const float*)d_in[6];
    const float* b_ih1 = (const float*)d_in[7];
    const float* b_hh1 = (const float*)d_in[8];
    const float* fc_W  = (const float*)d_in[9];
    const float* fc_b  = (const float*)d_in[10];
    float* out = (float*)d_out;
    unsigned short* ws = (unsigned short*)d_ws;    // 192 KB of pre-split fragments

    // 1) pre-split weight fragments into d_ws (contiguous per-lane runs)
    hipLaunchKernelGGL(prep_weights, dim3(24), dim3(256), 0, stream,
                       W_hh0, W_ih1, W_hh1, ws);

    // 2) main recurrent kernel
    const int B = in_sizes[0] / TT;          // 2048
    dim3 grid(B / NB), block(NT);            // 256 blocks x 512 threads
    hipLaunchKernelGGL(lstm2_mfma_kernel, grid, block, 0, stream,
                       x, ws, W_ih0, b_ih0, b_hh0, b_ih1, b_hh1, fc_W, fc_b, out);
}